// Round 2
// baseline (219.367 us; speedup 1.0000x reference)
//
#include <hip/hip_runtime.h>

#define CROPX 512
#define NN 510          // CROP - 2
#define BATCHX 32

constexpr float INV_DX   = 100.0f;     // 1/DX
constexpr float DT_F     = 0.001f;
constexpr float INV_DXDT = 100000.0f;  // 1/(DX*DT)
constexpr float INV_DX2  = 10000.0f;   // 1/DX^2

// Load 6 consecutive row elements per thread: own aligned float4 + 2 from the
// right neighbor lane (shfl); lane 63 loads the 2 halo scalars directly.
__device__ __forceinline__ void load_row6(const float* __restrict__ base, int r,
                                          int c0, int lane, float o[6]) {
    const float* rp = base + (size_t)r * CROPX + c0;
    const float4 q = *reinterpret_cast<const float4*>(rp);
    float nx = __shfl_down(q.x, 1, 64);
    float ny = __shfl_down(q.y, 1, 64);
    if (lane == 63) {
        const int lim = CROPX - 1 - c0;          // clamp (only matters at col 508)
        nx = rp[4 < lim ? 4 : lim];
        ny = rp[5 < lim ? 5 : lim];
    }
    o[0] = q.x; o[1] = q.y; o[2] = q.z; o[3] = q.w; o[4] = nx; o[5] = ny;
}

// -------------------- main interior kernel --------------------
// Wave = 64 lanes x 4 cols = 256 cols (cg picks which half). Each wave owns an
// 8-row tile; rows stream with full register carry (row r1 kept, r2 loaded).
__global__ __launch_bounds__(256) void pde_main(const float* __restrict__ g,
                                                const float* __restrict__ png,
                                                float* __restrict__ ws) {
    const int bb   = blockIdx.z;
    const int w    = threadIdx.x >> 6;
    const int lane = threadIdx.x & 63;
    const int tile = blockIdx.y * 4 + w;       // 0..63
    const int cg   = blockIdx.x;               // 0..1
    const int c0   = cg * 256 + lane * 4;      // first owned col (16B aligned)
    const int a0   = tile * 8;                 // first output row

    const float* u  = g + (size_t)bb * 3 * (CROPX * CROPX);
    const float* v  = u + CROPX * CROPX;
    const float* p  = v + CROPX * CROPX;
    const float* pn = png + (size_t)bb * (CROPX * CROPX);

    const bool edgelane = (cg == 1 && lane == 0);   // col 256: left col in other cg

    float u1[6], v1[6], p1[6], pn1[6];             // row r1 = a+1
    float fnuC[5], fnvC[5], dvdtC[4], ppN[4], vup[4];

    // ---- warmup: rows a0-1 (v only), a0, a0+1 ----
    {
        float ua[6], va[6], pa[6], pna[6];
        load_row6(u,  a0, c0, lane, ua);
        load_row6(v,  a0, c0, lane, va);
        load_row6(p,  a0, c0, lane, pa);
        load_row6(pn, a0, c0, lane, pna);
        load_row6(u,  a0 + 1, c0, lane, u1);
        load_row6(v,  a0 + 1, c0, lane, v1);
        load_row6(p,  a0 + 1, c0, lane, p1);
        load_row6(pn, a0 + 1, c0, lane, pn1);

        #pragma unroll
        for (int j = 0; j < 5; ++j)
            fnuC[j] = 0.5f * (va[j] + va[j + 1]) * 0.5f * (ua[j] + u1[j]) - (u1[j] - ua[j]);
        #pragma unroll
        for (int j = 1; j < 5; ++j) {
            float m = 0.5f * (va[j] + v1[j]);
            fnvC[j] = m * m - (v1[j] - va[j]);
        }
        #pragma unroll
        for (int k = 0; k < 4; ++k) { ppN[k] = pna[k + 1] - pa[k + 1]; vup[k] = va[k + 1]; }

        if (a0 > 0) {
            float vm[6];
            load_row6(v, a0 - 1, c0, lane, vm);
            float fev[5];
            #pragma unroll
            for (int j = 0; j < 5; ++j)
                fev[j] = 0.5f * (ua[j] + u1[j]) * 0.5f * (va[j] + va[j + 1]) - (va[j + 1] - va[j]);
            #pragma unroll
            for (int k = 0; k < 4; ++k) {
                float mm = 0.5f * (vm[k + 1] + va[k + 1]);
                float fnvm = mm * mm - (va[k + 1] - vm[k + 1]);
                dvdtC[k] = (-(fev[k + 1] - fev[k]) - (fnvC[k + 1] - fnvm)
                            - (p1[k + 1] - pa[k + 1])) * INV_DX;
            }
        } else {
            #pragma unroll
            for (int k = 0; k < 4; ++k) dvdtC[k] = 0.0f;
        }
    }

    float cont_acc = 0.0f, pois_acc = 0.0f;

    #pragma unroll
    for (int it = 0; it < 8; ++it) {
        const int a  = a0 + it;
        const int r1 = (a + 1 < CROPX) ? a + 1 : CROPX - 1;   // clamp only on masked tail
        const int r2 = (a + 2 < CROPX) ? a + 2 : CROPX - 1;

        float u2[6], v2[6], p2[6], pn2[6];
        load_row6(u,  r2, c0, lane, u2);
        load_row6(v,  r2, c0, lane, v2);
        load_row6(p,  r2, c0, lane, p2);
        load_row6(pn, r2, c0, lane, pn2);

        float uLeft = 0.0f;
        if (edgelane) uLeft = u[(size_t)r1 * CROPX + (c0 - 1)];

        // row-r1 fluxes at cols c0+j
        float FEu[5], FEv[5], FNu1[5], FNv1[5];
        #pragma unroll
        for (int j = 0; j < 5; ++j) {
            float ux = 0.5f * (u1[j] + u1[j + 1]);
            FEu[j] = ux * ux - (u1[j + 1] - u1[j]);
            float uy = 0.5f * (u1[j] + u2[j]);
            float vx = 0.5f * (v1[j] + v1[j + 1]);
            float prod = uy * vx;
            FEv[j]  = prod - (v1[j + 1] - v1[j]);
            FNu1[j] = prod - (u2[j] - u1[j]);
        }
        #pragma unroll
        for (int j = 1; j < 5; ++j) {
            float vy = 0.5f * (v1[j] + v2[j]);
            FNv1[j] = vy * vy - (v2[j] - v1[j]);
        }

        float dudt[4], dvdt[4];
        #pragma unroll
        for (int k = 0; k < 4; ++k) {
            dudt[k] = (-(FEu[k + 1] - FEu[k]) - (FNu1[k + 1] - fnuC[k + 1])
                       - (p1[k + 2] - p1[k + 1])) * INV_DX;
            dvdt[k] = (-(FEv[k + 1] - FEv[k]) - (FNv1[k + 1] - fnvC[k + 1])
                       - (p2[k + 1] - p1[k + 1])) * INV_DX;
        }

        // dudt(a, c0-1): from left lane; cg-boundary lane recomputes directly
        float dudtLm = __shfl_up(dudt[3], 1, 64);
        if (edgelane) {
            float uxm  = 0.5f * (uLeft + u1[0]);
            float FEuL = uxm * uxm - (u1[0] - uLeft);
            dudtLm = (-(FEu[0] - FEuL) - (FNu1[0] - fnuC[0]) - (p1[1] - p1[0])) * INV_DX;
        }

        #pragma unroll
        for (int k = 0; k < 4; ++k) {
            const int b = c0 + k;
            float ppC = pn1[k + 1] - p1[k + 1];
            float ppS = pn2[k + 1] - p2[k + 1];
            float ppW = pn1[k]     - p1[k];
            float ppE = pn1[k + 2] - p1[k + 2];
            float lap = 4.0f * ppC - ppE - ppW - ppS - ppN[k];
            float du_x = u1[k + 1] - u1[k];
            float dv_y = v1[k + 1] - vup[k];
            float dL  = (k == 0) ? dudtLm : dudt[k - 1];
            float dRm = (b <= NN - 2) ? dudt[k] : 0.0f;
            float dLm = (b >= 1)      ? dL      : 0.0f;
            float vCm = (a <= NN - 2) ? dvdt[k] : 0.0f;
            float vPm = (a >= 1)      ? dvdtC[k] : 0.0f;
            float bconv = (du_x + dv_y + DT_F * ((dRm - dLm) + (vCm - vPm))) * INV_DXDT;
            float pois  = lap * INV_DX2 + bconv;
            if (b < NN && a < NN) {
                cont_acc += fabsf((du_x + dv_y) * INV_DX);
                pois_acc += fabsf(pois);
            }
            ppN[k]   = ppC;          // becomes pp(a', b+1)
            vup[k]   = v1[k + 1];    // becomes v[a'][b+1]
            dvdtC[k] = dvdt[k];
        }
        #pragma unroll
        for (int j = 0; j < 5; ++j) { fnuC[j] = FNu1[j]; if (j >= 1) fnvC[j] = FNv1[j]; }
        #pragma unroll
        for (int j = 0; j < 6; ++j) { u1[j] = u2[j]; v1[j] = v2[j]; p1[j] = p2[j]; pn1[j] = pn2[j]; }
    }

    // ---- wave + block reduction, one atomic per block ----
    float c = cont_acc, q = pois_acc;
    #pragma unroll
    for (int off = 32; off > 0; off >>= 1) {
        c += __shfl_down(c, off, 64);
        q += __shfl_down(q, off, 64);
    }
    __shared__ float sred[8];
    if (lane == 0) { sred[w] = c; sred[4 + w] = q; }
    __syncthreads();
    if (threadIdx.x == 0) {
        atomicAdd(&ws[0], sred[0] + sred[1] + sred[2] + sred[3]);
        atomicAdd(&ws[1], sred[4] + sred[5] + sred[6] + sred[7]);
    }
}

// -------------------- boundary-condition partial sums --------------------
// Signed per-batch edge sums accumulate into ws[4 + 4*batch + role] from many
// blocks; abs() is deferred to pde_final (so no one-block-per-batch limit).
__global__ __launch_bounds__(256) void pde_bc(const float* __restrict__ g,
                                              float* __restrict__ ws) {
    const int bb    = blockIdx.y;
    const int slice = blockIdx.x;          // 0..7
    const int lane  = threadIdx.x & 63;
    const int role  = threadIdx.x >> 6;    // 0:y0 1:yL 2:x0 3:xL (one wave each)
    const int j     = slice * 64 + lane;   // 0..511

    const float* u = g + (size_t)bb * 3 * (CROPX * CROPX);
    const float* v = u + CROPX * CROPX;
    const float* p = v + CROPX * CROPX;

    const bool in9  = (j >= 1 && j <= NN - 1);   // 1..509
    const bool in10 = (j >= 1 && j <= NN);       // 1..510

    float val = 0.0f;
    if (role == 0) {
        if (in9)  val += u[j] + u[CROPX + j];
        if (in10) val += v[j] + p[j];
    } else if (role == 1) {
        if (in9)  val += 2.0f - u[(size_t)NN * CROPX + j] - u[(size_t)(NN + 1) * CROPX + j];
        if (in10) val += v[(size_t)(NN + 1) * CROPX + j] + p[(size_t)(NN + 1) * CROPX + j];
    } else if (role == 2) {
        if (in9)  val += v[(size_t)j * CROPX] + v[(size_t)j * CROPX + 1];
        if (in10) val += u[(size_t)j * CROPX] + p[(size_t)j * CROPX];
    } else {
        if (in9)  val += v[(size_t)j * CROPX + (CROPX - 1)] + v[(size_t)j * CROPX + (CROPX - 2)];
        if (in10) val += u[(size_t)j * CROPX + (CROPX - 1)] + p[(size_t)j * CROPX + (CROPX - 1)];
    }

    #pragma unroll
    for (int off = 32; off > 0; off >>= 1) val += __shfl_down(val, off, 64);
    if (lane == 0) atomicAdd(&ws[4 + bb * 4 + role], val);
}

// -------------------- final combine --------------------
__global__ void pde_final(const float* __restrict__ ws, float* __restrict__ out) {
    const int t = threadIdx.x;   // 64 threads
    float bc = 0.0f;
    if (t < BATCHX) {
        const float* wb = ws + 4 + t * 4;
        bc = fabsf(wb[0]) + fabsf(wb[1]) + fabsf(wb[2]) + fabsf(wb[3]);
    }
    #pragma unroll
    for (int off = 32; off > 0; off >>= 1) bc += __shfl_down(bc, off, 64);
    if (t == 0) {
        const float inv = 1.0f / ((float)BATCHX * NN * NN);
        out[0] = 0.4f * (ws[0] + ws[1]) * inv + 0.2f * bc;
    }
}

extern "C" void kernel_launch(void* const* d_in, const int* in_sizes, int n_in,
                              void* d_out, int out_size, void* d_ws, size_t ws_size,
                              hipStream_t stream) {
    const float* g  = (const float*)d_in[0];   // gen_output (32,3,512,512) f32
    const float* pn = (const float*)d_in[1];   // p_next_step (32,1,512,512) f32
    float* out = (float*)d_out;
    float* ws  = (float*)d_ws;

    hipMemsetAsync(ws, 0, (4 + BATCHX * 4) * sizeof(float), stream);

    dim3 gm(2, 16, 32);   // colgroup, supertile(4 waves of row-tiles), batch
    pde_main<<<gm, 256, 0, stream>>>(g, pn, ws);
    dim3 gb(8, 32);       // j-slice, batch
    pde_bc<<<gb, 256, 0, stream>>>(g, ws);
    pde_final<<<1, 64, 0, stream>>>(ws, out);
}

// Round 4
// 189.950 us; speedup vs baseline: 1.1549x; 1.1549x over previous
//
#include <hip/hip_runtime.h>

#define CROPX 512
#define NN 510          // CROP - 2
#define BATCHX 32

constexpr float INV_DX   = 100.0f;     // 1/DX
constexpr float DT_F     = 0.001f;
constexpr float INV_DXDT = 100000.0f;  // 1/(DX*DT)
constexpr float INV_DX2  = 10000.0f;   // 1/DX^2

// Load 6 consecutive row elements per thread: aligned float4 + 2 halo scalars
// loaded DIRECTLY (no shfl -> no vmcnt(0) serialization; all loads independent).
// Clamp to col 511 (only bites lane63/cg1, whose clamped values feed masked-out
// outputs only -- identical semantics to the shfl version).
__device__ __forceinline__ void load_row6(const float* __restrict__ base, int r,
                                          int c0, float o[6]) {
    const float* rp = base + (size_t)r * CROPX;
    const float4 q = *reinterpret_cast<const float4*>(rp + c0);
    int c4 = c0 + 4; if (c4 > CROPX - 1) c4 = CROPX - 1;
    int c5 = c0 + 5; if (c5 > CROPX - 1) c5 = CROPX - 1;
    float h0 = rp[c4];
    float h1 = rp[c5];
    o[0] = q.x; o[1] = q.y; o[2] = q.z; o[3] = q.w; o[4] = h0; o[5] = h1;
}

// -------------------- main interior kernel --------------------
// Wave = 64 lanes x 4 cols = 256 cols (cg picks which half). Each wave owns an
// 8-row tile; rows stream with full register carry (row r1 kept, r2 loaded).
__global__ __launch_bounds__(256, 4) void pde_main(const float* __restrict__ g,
                                                   const float* __restrict__ png,
                                                   float* __restrict__ ws) {
    const int bb   = blockIdx.z;
    const int w    = threadIdx.x >> 6;
    const int lane = threadIdx.x & 63;
    const int tile = blockIdx.y * 4 + w;       // 0..63
    const int cg   = blockIdx.x;               // 0..1
    const int c0   = cg * 256 + lane * 4;      // first owned col (16B aligned)
    const int a0   = tile * 8;                 // first output row

    const float* u  = g + (size_t)bb * 3 * (CROPX * CROPX);
    const float* v  = u + CROPX * CROPX;
    const float* p  = v + CROPX * CROPX;
    const float* pn = png + (size_t)bb * (CROPX * CROPX);

    const bool edgelane = (cg == 1 && lane == 0);   // col 256: left col in other cg

    float u1[6], v1[6], p1[6], pn1[6];             // row r1 = a+1
    float fnuC[5], fnvC[5], dvdtC[4], ppN[4], vup[4];

    // ---- warmup: rows a0-1 (v only), a0, a0+1 ----
    {
        float ua[6], va[6], pa[6], pna[6];
        load_row6(u,  a0, c0, ua);
        load_row6(v,  a0, c0, va);
        load_row6(p,  a0, c0, pa);
        load_row6(pn, a0, c0, pna);
        load_row6(u,  a0 + 1, c0, u1);
        load_row6(v,  a0 + 1, c0, v1);
        load_row6(p,  a0 + 1, c0, p1);
        load_row6(pn, a0 + 1, c0, pn1);

        #pragma unroll
        for (int j = 0; j < 5; ++j)
            fnuC[j] = 0.5f * (va[j] + va[j + 1]) * 0.5f * (ua[j] + u1[j]) - (u1[j] - ua[j]);
        #pragma unroll
        for (int j = 1; j < 5; ++j) {
            float m = 0.5f * (va[j] + v1[j]);
            fnvC[j] = m * m - (v1[j] - va[j]);
        }
        #pragma unroll
        for (int k = 0; k < 4; ++k) { ppN[k] = pna[k + 1] - pa[k + 1]; vup[k] = va[k + 1]; }

        if (a0 > 0) {
            float vm[6];
            load_row6(v, a0 - 1, c0, vm);
            float fev[5];
            #pragma unroll
            for (int j = 0; j < 5; ++j)
                fev[j] = 0.5f * (ua[j] + u1[j]) * 0.5f * (va[j] + va[j + 1]) - (va[j + 1] - va[j]);
            #pragma unroll
            for (int k = 0; k < 4; ++k) {
                float mm = 0.5f * (vm[k + 1] + va[k + 1]);
                float fnvm = mm * mm - (va[k + 1] - vm[k + 1]);
                dvdtC[k] = (-(fev[k + 1] - fev[k]) - (fnvC[k + 1] - fnvm)
                            - (p1[k + 1] - pa[k + 1])) * INV_DX;
            }
        } else {
            #pragma unroll
            for (int k = 0; k < 4; ++k) dvdtC[k] = 0.0f;
        }
    }

    float cont_acc = 0.0f, pois_acc = 0.0f;

    #pragma unroll
    for (int it = 0; it < 8; ++it) {
        const int a  = a0 + it;
        const int r1 = (a + 1 < CROPX) ? a + 1 : CROPX - 1;   // clamp only on masked tail
        const int r2 = (a + 2 < CROPX) ? a + 2 : CROPX - 1;

        // ---- batch ALL loads for this iteration first (independent, no x-lane) ----
        float u2[6], v2[6], p2[6], pn2[6];
        load_row6(u,  r2, c0, u2);
        load_row6(v,  r2, c0, v2);
        load_row6(p,  r2, c0, p2);
        load_row6(pn, r2, c0, pn2);

        float uLeft = 0.0f;
        if (edgelane) uLeft = u[(size_t)r1 * CROPX + (c0 - 1)];

        // row-r1 fluxes at cols c0+j
        float FEu[5], FEv[5], FNu1[5], FNv1[5];
        #pragma unroll
        for (int j = 0; j < 5; ++j) {
            float ux = 0.5f * (u1[j] + u1[j + 1]);
            FEu[j] = ux * ux - (u1[j + 1] - u1[j]);
            float uy = 0.5f * (u1[j] + u2[j]);
            float vx = 0.5f * (v1[j] + v1[j + 1]);
            float prod = uy * vx;
            FEv[j]  = prod - (v1[j + 1] - v1[j]);
            FNu1[j] = prod - (u2[j] - u1[j]);
        }
        #pragma unroll
        for (int j = 1; j < 5; ++j) {
            float vy = 0.5f * (v1[j] + v2[j]);
            FNv1[j] = vy * vy - (v2[j] - v1[j]);
        }

        float dudt[4], dvdt[4];
        #pragma unroll
        for (int k = 0; k < 4; ++k) {
            dudt[k] = (-(FEu[k + 1] - FEu[k]) - (FNu1[k + 1] - fnuC[k + 1])
                       - (p1[k + 2] - p1[k + 1])) * INV_DX;
            dvdt[k] = (-(FEv[k + 1] - FEv[k]) - (FNv1[k + 1] - fnvC[k + 1])
                       - (p2[k + 1] - p1[k + 1])) * INV_DX;
        }

        // dudt(a, c0-1): from left lane; cg-boundary lane recomputes directly
        float dudtLm = __shfl_up(dudt[3], 1, 64);
        if (edgelane) {
            float uxm  = 0.5f * (uLeft + u1[0]);
            float FEuL = uxm * uxm - (u1[0] - uLeft);
            dudtLm = (-(FEu[0] - FEuL) - (FNu1[0] - fnuC[0]) - (p1[1] - p1[0])) * INV_DX;
        }

        #pragma unroll
        for (int k = 0; k < 4; ++k) {
            const int b = c0 + k;
            float ppC = pn1[k + 1] - p1[k + 1];
            float ppS = pn2[k + 1] - p2[k + 1];
            float ppW = pn1[k]     - p1[k];
            float ppE = pn1[k + 2] - p1[k + 2];
            float lap = 4.0f * ppC - ppE - ppW - ppS - ppN[k];
            float du_x = u1[k + 1] - u1[k];
            float dv_y = v1[k + 1] - vup[k];
            float dL  = (k == 0) ? dudtLm : dudt[k - 1];
            float dRm = (b <= NN - 2) ? dudt[k] : 0.0f;
            float dLm = (b >= 1)      ? dL      : 0.0f;
            float vCm = (a <= NN - 2) ? dvdt[k] : 0.0f;
            float vPm = (a >= 1)      ? dvdtC[k] : 0.0f;
            float bconv = (du_x + dv_y + DT_F * ((dRm - dLm) + (vCm - vPm))) * INV_DXDT;
            float pois  = lap * INV_DX2 + bconv;
            if (b < NN && a < NN) {
                cont_acc += fabsf((du_x + dv_y) * INV_DX);
                pois_acc += fabsf(pois);
            }
            ppN[k]   = ppC;          // becomes pp(a', b+1)
            vup[k]   = v1[k + 1];    // becomes v[a'][b+1]
            dvdtC[k] = dvdt[k];
        }
        #pragma unroll
        for (int j = 0; j < 5; ++j) { fnuC[j] = FNu1[j]; if (j >= 1) fnvC[j] = FNv1[j]; }
        #pragma unroll
        for (int j = 0; j < 6; ++j) { u1[j] = u2[j]; v1[j] = v2[j]; p1[j] = p2[j]; pn1[j] = pn2[j]; }
    }

    // ---- wave + block reduction, one atomic per block ----
    float c = cont_acc, q = pois_acc;
    #pragma unroll
    for (int off = 32; off > 0; off >>= 1) {
        c += __shfl_down(c, off, 64);
        q += __shfl_down(q, off, 64);
    }
    __shared__ float sred[8];
    if (lane == 0) { sred[w] = c; sred[4 + w] = q; }
    __syncthreads();
    if (threadIdx.x == 0) {
        atomicAdd(&ws[0], sred[0] + sred[1] + sred[2] + sred[3]);
        atomicAdd(&ws[1], sred[4] + sred[5] + sred[6] + sred[7]);
    }
}

// -------------------- boundary-condition partial sums --------------------
// Signed per-batch edge sums accumulate into ws[4 + 4*batch + role] from many
// blocks; abs() is deferred to pde_final (so no one-block-per-batch limit).
__global__ __launch_bounds__(256) void pde_bc(const float* __restrict__ g,
                                              float* __restrict__ ws) {
    const int bb    = blockIdx.y;
    const int slice = blockIdx.x;          // 0..7
    const int lane  = threadIdx.x & 63;
    const int role  = threadIdx.x >> 6;    // 0:y0 1:yL 2:x0 3:xL (one wave each)
    const int j     = slice * 64 + lane;   // 0..511

    const float* u = g + (size_t)bb * 3 * (CROPX * CROPX);
    const float* v = u + CROPX * CROPX;
    const float* p = v + CROPX * CROPX;

    const bool in9  = (j >= 1 && j <= NN - 1);   // 1..509
    const bool in10 = (j >= 1 && j <= NN);       // 1..510

    float val = 0.0f;
    if (role == 0) {
        if (in9)  val += u[j] + u[CROPX + j];
        if (in10) val += v[j] + p[j];
    } else if (role == 1) {
        if (in9)  val += 2.0f - u[(size_t)NN * CROPX + j] - u[(size_t)(NN + 1) * CROPX + j];
        if (in10) val += v[(size_t)(NN + 1) * CROPX + j] + p[(size_t)(NN + 1) * CROPX + j];
    } else if (role == 2) {
        if (in9)  val += v[(size_t)j * CROPX] + v[(size_t)j * CROPX + 1];
        if (in10) val += u[(size_t)j * CROPX] + p[(size_t)j * CROPX];
    } else {
        if (in9)  val += v[(size_t)j * CROPX + (CROPX - 1)] + v[(size_t)j * CROPX + (CROPX - 2)];
        if (in10) val += u[(size_t)j * CROPX + (CROPX - 1)] + p[(size_t)j * CROPX + (CROPX - 1)];
    }

    #pragma unroll
    for (int off = 32; off > 0; off >>= 1) val += __shfl_down(val, off, 64);
    if (lane == 0) atomicAdd(&ws[4 + bb * 4 + role], val);
}

// -------------------- final combine --------------------
__global__ void pde_final(const float* __restrict__ ws, float* __restrict__ out) {
    const int t = threadIdx.x;   // 64 threads
    float bc = 0.0f;
    if (t < BATCHX) {
        const float* wb = ws + 4 + t * 4;
        bc = fabsf(wb[0]) + fabsf(wb[1]) + fabsf(wb[2]) + fabsf(wb[3]);
    }
    #pragma unroll
    for (int off = 32; off > 0; off >>= 1) bc += __shfl_down(bc, off, 64);
    if (t == 0) {
        const float inv = 1.0f / ((float)BATCHX * NN * NN);
        out[0] = 0.4f * (ws[0] + ws[1]) * inv + 0.2f * bc;
    }
}

extern "C" void kernel_launch(void* const* d_in, const int* in_sizes, int n_in,
                              void* d_out, int out_size, void* d_ws, size_t ws_size,
                              hipStream_t stream) {
    const float* g  = (const float*)d_in[0];   // gen_output (32,3,512,512) f32
    const float* pn = (const float*)d_in[1];   // p_next_step (32,1,512,512) f32
    float* out = (float*)d_out;
    float* ws  = (float*)d_ws;

    hipMemsetAsync(ws, 0, (4 + BATCHX * 4) * sizeof(float), stream);

    dim3 gm(2, 16, 32);   // colgroup, supertile(4 waves of row-tiles), batch
    pde_main<<<gm, 256, 0, stream>>>(g, pn, ws);
    dim3 gb(8, 32);       // j-slice, batch
    pde_bc<<<gb, 256, 0, stream>>>(g, ws);
    pde_final<<<1, 64, 0, stream>>>(ws, out);
}